// Round 3
// baseline (73.956 us; speedup 1.0000x reference)
//
#include <hip/hip_runtime.h>

// Geometry (fixed by the reference)
#define FDIM 16
#define SDIM 512
#define ODIM 32
#define SF   (SDIM * FDIM)   // 8192 floats per batch row
#define PAIRS 512            // (f,o) pairs; W[s*512 + p], p = f*32+o
#define NB   2               // batches per block
#define NTH  512             // threads per block (8 waves)
#define NSL  4               // s-slices (th = t>>7)
#define SSL  (SDIM / NSL)    // 128 shifts per slice
#define NBLK (256 / NB)      // 128 blocks

// Single fused kernel: each block owns NB=2 batches and iterates ALL 512
// shifts, so there are no partials, no second kernel, no workspace use.
// W is only 1 MB -> L2-resident per XCD; per-block W traffic = 1 MB,
// total 128 MB of L2 reads (~3.7 us at 34.5 TB/s), overlapped with
// ~3.4 us of VALU (134M lane-ops on 128 CUs).
//
// Thread map (same as the proven phase1): tq = t&127 owns pairs
// 4tq..4tq+3 (single f = tq>>3, 8-lane LDS broadcast of x); th = t>>7
// picks one of 4 s-slices of 128 shifts. Slices combine through LDS with
// write-once buffers and 3 barriers (max is exact, any combine order is
// bit-identical; the f-SUM order in the epilogue is kept identical to the
// proven kernel).
__global__ __launch_bounds__(NTH) void max_layer_fused(
    const float* __restrict__ x, const float* __restrict__ W,
    const float* __restrict__ bias, float* __restrict__ out) {
  __shared__ float  xs[NB * SF];                // 64 KB, [b][s][f]
  __shared__ float4 red[(NSL - 1) * NB * 128];  // 12 KB, slices th=1..3
  __shared__ float  redf[NB * PAIRS];           // 4 KB, final max per (b,p)

  const int t  = threadIdx.x;
  const int b0 = blockIdx.x * NB;

  // Stage x for both batches: 64 KB contiguous, fully coalesced float4.
  const float4* xin = (const float4*)x + (size_t)b0 * (SF / 4);
  float4* xs4 = (float4*)xs;
#pragma unroll
  for (int k = 0; k < NB * SF / 4 / NTH; ++k) {
    const int i = t + k * NTH;
    xs4[i] = xin[i];
  }
  __syncthreads();

  const int tq = t & 127;
  const int th = t >> 7;          // s-slice 0..3
  const int f  = tq >> 3;         // f of owned pairs

  const float NEG = -3.402823466e+38f;
  float4 macc[NB];
#pragma unroll
  for (int b = 0; b < NB; ++b) macc[b] = make_float4(NEG, NEG, NEG, NEG);

  const float4* wp = (const float4*)W + tq;

#pragma unroll 4
  for (int j = 0; j < SSL; ++j) {
    const int s = th * SSL + j;
    float4 w = wp[(size_t)s * (PAIRS / 4)];   // 2KB W row spread over 128 lanes
    const float* xp = xs + s * FDIM + f;
#pragma unroll
    for (int b = 0; b < NB; ++b) {
      float xv = xp[b * SF];                  // LDS broadcast (8 lanes/addr)
      macc[b].x = fmaxf(macc[b].x, xv * w.x);
      macc[b].y = fmaxf(macc[b].y, xv * w.y);
      macc[b].z = fmaxf(macc[b].z, xv * w.z);
      macc[b].w = fmaxf(macc[b].w, xv * w.w);
    }
  }

  // Slices 1..3 publish; slice 0 combines; epilogue reads. Every LDS
  // location is written exactly once per phase, barriers between phases.
  if (th >= 1) {
#pragma unroll
    for (int b = 0; b < NB; ++b)
      red[((th - 1) * NB + b) * 128 + tq] = macc[b];
  }
  __syncthreads();
  if (th == 0) {
#pragma unroll
    for (int b = 0; b < NB; ++b) {
      float4 o = macc[b];
#pragma unroll
      for (int sl = 0; sl < NSL - 1; ++sl) {
        float4 v = red[(sl * NB + b) * 128 + tq];
        o.x = fmaxf(o.x, v.x);
        o.y = fmaxf(o.y, v.y);
        o.z = fmaxf(o.z, v.z);
        o.w = fmaxf(o.w, v.w);
      }
      ((float4*)redf)[b * 128 + tq] = o;
    }
  }
  __syncthreads();

  // out[b][o] = relu(bias[o] + sum_f redf[b][f*32+o]); f order 0..15
  // identical to the proven phase2 (bit-exact sum order).
  if (t < NB * ODIM) {
    const int b = t >> 5;
    const int o = t & 31;
    float s = bias[o];
#pragma unroll
    for (int ff = 0; ff < FDIM; ++ff) s += redf[b * PAIRS + ff * ODIM + o];
    out[(size_t)(b0 + b) * ODIM + o] = fmaxf(s, 0.0f);
  }
}

extern "C" void kernel_launch(void* const* d_in, const int* in_sizes, int n_in,
                              void* d_out, int out_size, void* d_ws, size_t ws_size,
                              hipStream_t stream) {
  const float* x    = (const float*)d_in[0];
  const float* W    = (const float*)d_in[1];
  const float* bias = (const float*)d_in[2];
  float* out        = (float*)d_out;
  (void)d_ws; (void)ws_size;

  max_layer_fused<<<dim3(NBLK), dim3(NTH), 0, stream>>>(x, W, bias, out);
}

// Round 4
// 69.341 us; speedup vs baseline: 1.0666x; 1.0666x over previous
//
#include <hip/hip_runtime.h>

// Geometry (fixed by the reference)
#define FDIM 16
#define SDIM 512
#define ODIM 32
#define SF   (SDIM * FDIM)   // 8192 floats per batch row
#define PAIRS 512            // (f,o) pairs; W[s*512 + p], p = f*32+o
#define NB   8               // batches per block (W reuse factor)
#define SC   32              // shifts per block
#define NSC  (SDIM / SC)     // 16 s-chunks
#define NBG  (256 / NB)      // 32 batch groups

// Phase 1: partial max over an s-chunk, for NB batches x all 512 pairs.
// Thread tq (=t&127) owns pairs 4tq..4tq+3 (one f); th (=t>>7) splits the
// 32-s chunk in half. Each W float4 is loaded ONCE and reused across the
// NB=8 batch accumulators -> W L2 traffic = (256/NB) MB = 32 MB total.
__global__ __launch_bounds__(256) void max_layer_phase1(
    const float* __restrict__ x, const float* __restrict__ W,
    float* __restrict__ part) {
  __shared__ float xs[NB * SC * FDIM];  // 16 KB, [b][s][f]
  __shared__ float red[NB * PAIRS];     // 16 KB, th=1 partials

  const int t  = threadIdx.x;
  const int bg = blockIdx.x / NSC;
  const int sc = blockIdx.x % NSC;

  // Stage x chunk: per b, 2 KB contiguous; fully coalesced float4.
  const float4* xin = (const float4*)x;
  float4* xs4 = (float4*)xs;
  for (int i = t; i < NB * SC * FDIM / 4; i += 256) {
    int b   = i / (SC * FDIM / 4);   // /128
    int off = i % (SC * FDIM / 4);
    xs4[i] = xin[(size_t)(bg * NB + b) * (SF / 4) + sc * (SC * FDIM / 4) + off];
  }
  __syncthreads();

  const int tq = t & 127;
  const int th = t >> 7;          // s-half 0/1
  const int f  = tq >> 3;         // f of owned pairs

  const float NEG = -3.402823466e+38f;
  float4 macc[NB];
#pragma unroll
  for (int b = 0; b < NB; ++b) macc[b] = make_float4(NEG, NEG, NEG, NEG);

  const float4* wp = (const float4*)W + (size_t)(sc * SC) * (PAIRS / 4) + tq;

#pragma unroll 4
  for (int j = 0; j < SC / 2; ++j) {
    const int s = th * (SC / 2) + j;
    float4 w = wp[s * (PAIRS / 4)];      // one 2KB W row / s, shared by 2 waves
    const float* xp = xs + s * FDIM + f;
#pragma unroll
    for (int b = 0; b < NB; ++b) {
      float xv = xp[b * SC * FDIM];      // LDS broadcast (8 lanes/addr)
      macc[b].x = fmaxf(macc[b].x, xv * w.x);
      macc[b].y = fmaxf(macc[b].y, xv * w.y);
      macc[b].z = fmaxf(macc[b].z, xv * w.z);
      macc[b].w = fmaxf(macc[b].w, xv * w.w);
    }
  }

  // Combine the two s-halves, write partials: part[(b)*NSC + sc][p]
  if (th == 1) {
#pragma unroll
    for (int b = 0; b < NB; ++b) ((float4*)red)[b * 128 + tq] = macc[b];
  }
  __syncthreads();
  if (th == 0) {
#pragma unroll
    for (int b = 0; b < NB; ++b) {
      float4 o = ((float4*)red)[b * 128 + tq];
      o.x = fmaxf(o.x, macc[b].x);
      o.y = fmaxf(o.y, macc[b].y);
      o.z = fmaxf(o.z, macc[b].z);
      o.w = fmaxf(o.w, macc[b].w);
      ((float4*)part)[((size_t)(bg * NB + b) * NSC + sc) * (PAIRS / 4) + tq] = o;
    }
  }
}

// Phase 2: max over the 16 chunk-partials per (b,p), then f-sum + bias + relu.
__global__ __launch_bounds__(256) void max_layer_phase2(
    const float* __restrict__ part, const float* __restrict__ bias,
    float* __restrict__ out) {
  __shared__ float red[PAIRS];
  const int t = threadIdx.x;
  const int b = blockIdx.x;
  const float* pb = part + (size_t)b * NSC * PAIRS;
  for (int p = t; p < PAIRS; p += 256) {
    float m = pb[p];
#pragma unroll
    for (int c = 1; c < NSC; ++c) m = fmaxf(m, pb[c * PAIRS + p]);
    red[p] = m;
  }
  __syncthreads();
  if (t < ODIM) {
    float s = bias[t];
#pragma unroll
    for (int ff = 0; ff < FDIM; ++ff) s += red[ff * ODIM + t];
    out[b * ODIM + t] = fmaxf(s, 0.0f);
  }
}

extern "C" void kernel_launch(void* const* d_in, const int* in_sizes, int n_in,
                              void* d_out, int out_size, void* d_ws, size_t ws_size,
                              hipStream_t stream) {
  const float* x    = (const float*)d_in[0];
  const float* W    = (const float*)d_in[1];
  const float* bias = (const float*)d_in[2];
  float* out        = (float*)d_out;
  float* part       = (float*)d_ws;   // 256*16*512*4 = 8 MB of scratch

  max_layer_phase1<<<dim3(NBG * NSC), dim3(256), 0, stream>>>(x, W, part);
  max_layer_phase2<<<dim3(256), dim3(256), 0, stream>>>(part, bias, out);
}